// Round 3
// baseline (498.693 us; speedup 1.0000x reference)
//
#include <hip/hip_runtime.h>

// AsynchronousGRUActor fused kernel — MI355X gfx950, v4.
// vs v2 (186 us measured): (1) 768-thread block -> 12 waves/CU share the
// 66 KB LDS weight image (was 8); (2) per-wave scratch collapsed to ONE
// 16x68 f32 buffer reused three times per tile (a -> h-transpose -> h_new
// in place; per-wave DS ops are in-order, lgkmcnt fences only); (3) next-x
// prefetch issued mid-tile right after phase 1 consumes current x, next-h
// after phase 2 consumes current h -> only one x/h batch live at a time,
// fits the 170-VGPR budget of 3 waves/SIMD without spill; (4) biases in LDS.
// vs v3 (never benched): LDS back under 128 KiB proven envelope, no forced
// 128-VGPR spill, no inline-asm cvt (f2b RNE kept bit-identical to v1/v2).

#define BB   500000
#define OBSN 128
#define HD   64
#define ADIM 16
#define NTIL (BB / 16)      // 31250 row-tiles
#define GRID 256
#define WPB  12             // waves per block
#define NWAVE (GRID * WPB)  // 3072 waves, ~10.2 tiles each

typedef __attribute__((ext_vector_type(8))) short short8;
typedef __attribute__((ext_vector_type(4))) float f32x4;

__device__ __forceinline__ unsigned short f2b(float f) {
  union { float f; unsigned u; } c; c.f = f;
  return (unsigned short)((c.u + 0x7fffu + ((c.u >> 16) & 1u)) >> 16);  // RNE
}
__device__ __forceinline__ unsigned pk2(float a, float b) {
  return (unsigned)f2b(a) | ((unsigned)f2b(b) << 16);
}
__device__ __forceinline__ short8 cvt_frag(float4 a, float4 b) {
  union { short8 v; unsigned u[4]; } t;
  t.u[0] = pk2(a.x, a.y); t.u[1] = pk2(a.z, a.w);
  t.u[2] = pk2(b.x, b.y); t.u[3] = pk2(b.z, b.w);
  return t.v;
}
__device__ __forceinline__ float fsigmoid(float x) {
  return __builtin_amdgcn_rcpf(1.f + __builtin_amdgcn_exp2f(-1.44269504f * x));
}
__device__ __forceinline__ float ftanh(float x) {
  return 1.f - 2.f * __builtin_amdgcn_rcpf(1.f + __builtin_amdgcn_exp2f(2.88539008f * x));
}

// d_ws layout (ushort), PRE-SWIZZLED within each row: position [n][k'] holds
// source element [n][k' ^ ((n&7)<<3)].  Regions: W1[64][128] @0 |
// WRZ[128][128] @8192 (cols 0:64 = w_ih rows 0:128, cols 64:128 = w_hh rows
// 0:128) | WIN[64][64] @24576 | WHN[64][64] @28672 | W2[16][64] @32768.
__global__ void convert_weights(const float* __restrict__ fc1_w,
                                const float* __restrict__ w_ih,
                                const float* __restrict__ w_hh,
                                const float* __restrict__ fc2_w,
                                unsigned short* __restrict__ ws) {
  int i = blockIdx.x * 256 + threadIdx.x;
  if (i < 8192) {
    int n = i >> 7, k = (i & 127) ^ ((n & 7) << 3);
    ws[i] = f2b(fc1_w[n * 128 + k]);
  } else if (i < 24576) {
    int j = i - 8192, n = j >> 7, k = (j & 127) ^ ((n & 7) << 3);
    float v = (k < 64) ? w_ih[n * 64 + k] : w_hh[n * 64 + (k - 64)];
    ws[i] = f2b(v);
  } else if (i < 28672) {
    int j = i - 24576, n = j >> 6, k = (j & 63) ^ ((n & 7) << 3);
    ws[i] = f2b(w_ih[8192 + n * 64 + k]);
  } else if (i < 32768) {
    int j = i - 28672, n = j >> 6, k = (j & 63) ^ ((n & 7) << 3);
    ws[i] = f2b(w_hh[8192 + n * 64 + k]);
  } else if (i < 33792) {
    int j = i - 32768, n = j >> 6, k = (j & 63) ^ ((n & 7) << 3);
    ws[i] = f2b(fc2_w[n * 64 + k]);
  }
}

struct Batch {        // x + mask stream for one tile (h handled separately)
  float4 x[8];        // 16 rows x 128 cols of x (this lane's fragment rows)
  int4   am4;         // active_masks for this lane's 4 output rows
};

#define LDS_FENCE() asm volatile("s_waitcnt lgkmcnt(0)" ::: "memory")
#define CFENCE()    asm volatile("" ::: "memory")   // compiler-only order pin

__global__ __launch_bounds__(768, 3) void gru_actor_main(
    const float* __restrict__ x, const float* __restrict__ hs,
    const int* __restrict__ am,
    const float* __restrict__ fc1_b, const float* __restrict__ b_ih,
    const float* __restrict__ b_hh, const float* __restrict__ fc2_b,
    const unsigned short* __restrict__ wb, float* __restrict__ out) {
  __shared__ __align__(16) unsigned short lw[33792];     // weights, swizzled (66 KB)
  __shared__ __align__(16) float wsb_all[WPB][16 * 68];  // per-wave f32 scratch (51 KB)
  __shared__ float bias_lds[336]; // b1[0:64) br[64:128) bz[128:192) bi[192:256) bh[256:320) b2[320:336)

  const int tid = threadIdx.x;
#pragma unroll
  for (int i = 0; i < 6; ++i) {   // linear 16B copy: 33792 ushorts = 4224 chunks
    int c = tid + i * 768;
    if (c < 4224) ((short8*)lw)[c] = ((const short8*)wb)[c];
  }
  if (tid < 64)       bias_lds[tid] = fc1_b[tid];
  else if (tid < 128) { int i = tid - 64;  bias_lds[tid] = b_ih[i] + b_hh[i]; }
  else if (tid < 192) { int i = tid - 128; bias_lds[tid] = b_ih[64 + i] + b_hh[64 + i]; }
  else if (tid < 256) { int i = tid - 192; bias_lds[tid] = b_ih[128 + i]; }
  else if (tid < 320) { int i = tid - 256; bias_lds[tid] = b_hh[128 + i]; }
  else if (tid < 336) bias_lds[tid] = fc2_b[tid - 320];
  __syncthreads();                // only barrier in the kernel

  const int wv = tid >> 6, lane = tid & 63;
  const int col = lane & 15, quad = lane >> 4;
  const int sw = (col & 7) << 3;  // weight-row&7 == col&7 for every row we touch
  float* wsb = wsb_all[wv];
  const f32x4 zero4 = {0.f, 0.f, 0.f, 0.f};

  auto pf_xam = [&](Batch& b, int t) {
    const float* xp = x + (size_t)(t * 16 + col) * OBSN + quad * 8;
#pragma unroll
    for (int kt = 0; kt < 4; ++kt) {
      b.x[2 * kt]     = *(const float4*)(xp + kt * 32);
      b.x[2 * kt + 1] = *(const float4*)(xp + kt * 32 + 4);
    }
    b.am4 = *(const int4*)(am + t * 16 + quad * 4);
  };
  auto pf_h = [&](float4* h, int t) {
    const float* hp = hs + (size_t)(t * 16 + col) * HD + quad * 8;
#pragma unroll
    for (int kt = 0; kt < 2; ++kt) {
      h[2 * kt]     = *(const float4*)(hp + kt * 32);
      h[2 * kt + 1] = *(const float4*)(hp + kt * 32 + 4);
    }
  };

  // process tile t; issues next tile's x-prefetch after phase 1 (x dead) and
  // next tile's h-prefetch after phase 2's K-loop (h dead).
  auto process = [&](const Batch& bt, const float4* hcur, int t,
                     Batch& bnxt, float4* hnxt, int tnext) {
    const int ampk = (bt.am4.x != 0) | ((bt.am4.y != 0) << 1) |
                     ((bt.am4.z != 0) << 2) | ((bt.am4.w != 0) << 3);
    // ---- Phase 1: a = tanh(x @ fc1_w^T + b1) -> wsb (f32, row-major) ----
    f32x4 accA[4] = {zero4, zero4, zero4, zero4};
#pragma unroll
    for (int kt = 0; kt < 4; ++kt) {
      short8 af = cvt_frag(bt.x[2 * kt], bt.x[2 * kt + 1]);
#pragma unroll
      for (int nt = 0; nt < 4; ++nt) {
        short8 bf = *(const short8*)(lw + (nt * 16 + col) * 128 + ((kt * 32 + quad * 8) ^ sw));
        accA[nt] = __builtin_amdgcn_mfma_f32_16x16x32_bf16(af, bf, accA[nt], 0, 0, 0);
      }
    }
    // current x consumed -> issue next tile's x/mask stream (covers ph2..next ph1)
    pf_xam(bnxt, tnext);
    __builtin_amdgcn_sched_barrier(0);
#pragma unroll
    for (int nt = 0; nt < 4; ++nt) {
      float b1 = bias_lds[nt * 16 + col];
#pragma unroll
      for (int rg = 0; rg < 4; ++rg)
        wsb[(quad * 4 + rg) * 68 + nt * 16 + col] = ftanh(accA[nt][rg] + b1);
    }
    LDS_FENCE();
    // ---- Phase 2: rz = [a,h] @ WRZ^T ; i_n = a @ WIN^T ; h_n = h @ WHN^T ----
    f32x4 rz[8]  = {zero4, zero4, zero4, zero4, zero4, zero4, zero4, zero4};
    f32x4 gin[4] = {zero4, zero4, zero4, zero4};
    f32x4 ghn[4] = {zero4, zero4, zero4, zero4};
    float4 alo0 = *(const float4*)(wsb + col * 68 + quad * 8);
    float4 ahi0 = *(const float4*)(wsb + col * 68 + quad * 8 + 4);
    float4 alo1 = *(const float4*)(wsb + col * 68 + 32 + quad * 8);
    float4 ahi1 = *(const float4*)(wsb + col * 68 + 32 + quad * 8 + 4);
    short8 afa0 = cvt_frag(alo0, ahi0);
    short8 afa1 = cvt_frag(alo1, ahi1);
#pragma unroll
    for (int kt = 0; kt < 2; ++kt) {  // K 0..63 : a
      short8 af = kt ? afa1 : afa0;
#pragma unroll
      for (int nt = 0; nt < 8; ++nt) {
        short8 bf = *(const short8*)(lw + 8192 + (nt * 16 + col) * 128 + ((kt * 32 + quad * 8) ^ sw));
        rz[nt] = __builtin_amdgcn_mfma_f32_16x16x32_bf16(af, bf, rz[nt], 0, 0, 0);
      }
#pragma unroll
      for (int nt = 0; nt < 4; ++nt) {
        short8 bf = *(const short8*)(lw + 24576 + (nt * 16 + col) * 64 + ((kt * 32 + quad * 8) ^ sw));
        gin[nt] = __builtin_amdgcn_mfma_f32_16x16x32_bf16(af, bf, gin[nt], 0, 0, 0);
      }
    }
#pragma unroll
    for (int kt = 0; kt < 2; ++kt) {  // K 64..127 : h
      short8 af = cvt_frag(hcur[2 * kt], hcur[2 * kt + 1]);
#pragma unroll
      for (int nt = 0; nt < 8; ++nt) {
        short8 bf = *(const short8*)(lw + 8192 + (nt * 16 + col) * 128 + 64 + ((kt * 32 + quad * 8) ^ sw));
        rz[nt] = __builtin_amdgcn_mfma_f32_16x16x32_bf16(af, bf, rz[nt], 0, 0, 0);
      }
#pragma unroll
      for (int nt = 0; nt < 4; ++nt) {
        short8 bf = *(const short8*)(lw + 28672 + (nt * 16 + col) * 64 + ((kt * 32 + quad * 8) ^ sw));
        ghn[nt] = __builtin_amdgcn_mfma_f32_16x16x32_bf16(af, bf, ghn[nt], 0, 0, 0);
      }
    }
    // a is consumed -> overwrite wsb with the h transpose (f32, same layout).
    CFENCE();   // keep the a-frag DS reads above these DS writes
#pragma unroll
    for (int kt = 0; kt < 2; ++kt) {
      *(float4*)(wsb + col * 68 + kt * 32 + quad * 8)     = hcur[2 * kt];
      *(float4*)(wsb + col * 68 + kt * 32 + quad * 8 + 4) = hcur[2 * kt + 1];
    }
    // hcur is dead: issue next tile's h stream (lands during gates/ph3/ph1).
    pf_h(hnxt, tnext);
    __builtin_amdgcn_sched_barrier(0);
    LDS_FENCE();
    // ---- Gates + masked update; h_new written in place (f32) ----
#pragma unroll
    for (int nt = 0; nt < 4; ++nt) {
      int c = nt * 16 + col;
      float br = bias_lds[64 + c], bz = bias_lds[128 + c];
      float bi = bias_lds[192 + c], bh = bias_lds[256 + c];
#pragma unroll
      for (int rg = 0; rg < 4; ++rg) {
        float r = fsigmoid(rz[nt][rg] + br);
        float z = fsigmoid(rz[nt + 4][rg] + bz);
        float n = ftanh(gin[nt][rg] + bi + r * (ghn[nt][rg] + bh));
        float hprev = wsb[(quad * 4 + rg) * 68 + c];
        float hu = (1.f - z) * n + z * hprev;
        wsb[(quad * 4 + rg) * 68 + c] = ((ampk >> rg) & 1) ? hu : hprev;
      }
    }
    LDS_FENCE();
    // ---- Phase 3: read h_new rows once -> coalesced store + logits MFMA ----
    float4 rlo0 = *(const float4*)(wsb + col * 68 + quad * 8);
    float4 rhi0 = *(const float4*)(wsb + col * 68 + quad * 8 + 4);
    float4 rlo1 = *(const float4*)(wsb + col * 68 + 32 + quad * 8);
    float4 rhi1 = *(const float4*)(wsb + col * 68 + 32 + quad * 8 + 4);
    float* op = out + (size_t)BB * ADIM + (size_t)(t * 16 + col) * HD + quad * 8;
    *(float4*)(op)          = rlo0;
    *(float4*)(op + 4)      = rhi0;
    *(float4*)(op + 32)     = rlo1;
    *(float4*)(op + 32 + 4) = rhi1;
    f32x4 acc2 = zero4;
    {
      short8 af0 = cvt_frag(rlo0, rhi0);
      short8 bf0 = *(const short8*)(lw + 32768 + col * 64 + ((quad * 8) ^ sw));
      acc2 = __builtin_amdgcn_mfma_f32_16x16x32_bf16(af0, bf0, acc2, 0, 0, 0);
      short8 af1 = cvt_frag(rlo1, rhi1);
      short8 bf1 = *(const short8*)(lw + 32768 + col * 64 + ((32 + quad * 8) ^ sw));
      acc2 = __builtin_amdgcn_mfma_f32_16x16x32_bf16(af1, bf1, acc2, 0, 0, 0);
    }
    float b2 = bias_lds[320 + col];
#pragma unroll
    for (int rg = 0; rg < 4; ++rg)
      out[(size_t)(t * 16 + quad * 4 + rg) * ADIM + col] = acc2[rg] + b2;
  };

  // Grid-stride tile loop, two-body unrolled for register double-buffering.
  // Prefetches are UNCONDITIONAL (self-tile dummy on the last iteration) so
  // the outstanding-VMEM count is path-independent.
  int t = blockIdx.x * WPB + wv;
  Batch A, B;
  float4 hA[4], hB[4];
  pf_xam(A, t);
  pf_h(hA, t);
  for (;;) {
    int tn = t + NWAVE;
    int ts = (tn < NTIL) ? tn : t;
    process(A, hA, t, B, hB, ts);   // issues pf_xam(B,ts) + pf_h(hB,ts) mid-tile
    if (tn >= NTIL) break;
    t = tn;
    tn = t + NWAVE;
    ts = (tn < NTIL) ? tn : t;
    process(B, hB, t, A, hA, ts);
    if (tn >= NTIL) break;
    t = tn;
  }
}

extern "C" void kernel_launch(void* const* d_in, const int* in_sizes, int n_in,
                              void* d_out, int out_size, void* d_ws, size_t ws_size,
                              hipStream_t stream) {
  const float* x     = (const float*)d_in[0];
  const float* hsp   = (const float*)d_in[1];
  const int*   amp   = (const int*)d_in[2];
  const float* fc1_w = (const float*)d_in[3];
  const float* fc1_b = (const float*)d_in[4];
  const float* w_ih  = (const float*)d_in[5];
  const float* w_hh  = (const float*)d_in[6];
  const float* b_ih  = (const float*)d_in[7];
  const float* b_hh  = (const float*)d_in[8];
  const float* fc2_w = (const float*)d_in[9];
  const float* fc2_b = (const float*)d_in[10];
  unsigned short* wb = (unsigned short*)d_ws;
  float* out = (float*)d_out;

  convert_weights<<<dim3(132), dim3(256), 0, stream>>>(fc1_w, w_ih, w_hh, fc2_w, wb);
  gru_actor_main<<<dim3(GRID), dim3(768), 0, stream>>>(
      x, hsp, amp, fc1_b, b_ih, b_hh, fc2_b, wb, out);
}